// Round 1
// baseline (773.845 us; speedup 1.0000x reference)
//
#include <hip/hip_runtime.h>
#include <math.h>

#define MULC 256
#define ROWF 2304   // 9*MUL floats per node row
#define ROW4 576    // float4s per row

// ---------------------------------------------------------------------------
// Kernel 1: fold W_lin @ W_tp into a single expanded weight vector W_full[2304]
//   W_full[u]            = (W_lin0[u,:]·W_tp0) * alpha*lin_norm
//   W_full[256+u*3+i]    = (W_lin1[u,:]·W_tp1) * alpha*lin_norm/sqrt(3)
//   W_full[1024+u*5+i]   = (W_lin2[u,:]·W_tp2) * alpha*lin_norm/sqrt(5)
// grid: 3*256 blocks of 64 threads; block b -> (mat = b>>8, u = b&255)
// ---------------------------------------------------------------------------
__global__ __launch_bounds__(64) void build_wfull_kernel(
    const float* __restrict__ Wl0, const float* __restrict__ Wl1,
    const float* __restrict__ Wl2, const float* __restrict__ Wt0,
    const float* __restrict__ Wt1, const float* __restrict__ Wt2,
    float* __restrict__ wfull) {
  const int b    = blockIdx.x;
  const int mat  = b >> 8;
  const int u    = b & 255;
  const int lane = threadIdx.x;  // 0..63

  const float* __restrict__ Wl = (mat == 0) ? Wl0 : (mat == 1) ? Wl1 : Wl2;
  const float* __restrict__ Wt = (mat == 0) ? Wt0 : (mat == 1) ? Wt1 : Wt2;

  float s = 0.f;
#pragma unroll
  for (int t = 0; t < 4; ++t) {
    const int v = lane + 64 * t;
    s = fmaf(Wl[u * MULC + v], Wt[v], s);
  }
#pragma unroll
  for (int off = 32; off > 0; off >>= 1) s += __shfl_down(s, off, 64);

  if (lane == 0) {
    const float base = 0.0625f / sqrtf(768.0f);  // lin_norm * alpha
    if (mat == 0) {
      wfull[u] = s * base;
    } else if (mat == 1) {
      const float sv = s * base * (1.0f / sqrtf(3.0f));
#pragma unroll
      for (int i = 0; i < 3; ++i) wfull[256 + u * 3 + i] = sv;
    } else {
      const float sv = s * base * (1.0f / sqrtf(5.0f));
#pragma unroll
      for (int i = 0; i < 5; ++i) wfull[1024 + u * 5 + i] = sv;
    }
  }
}

// ---------------------------------------------------------------------------
// Kernel 2: streaming weighted reduction.
//   energy[z] = sum_e x[z,e] * W_full[e] * ch[z, cidx(e)]
// One wave per row (grid-stride). Lane l handles float4 chunks f = l + 64*j,
// j=0..8. Weights live in 36 VGPRs; charge indices (*4, byte addrs for
// ds_bpermute) packed 4-per-int in 9 VGPRs. Charges for the row are loaded by
// lanes 0..8 and fetched per-element with ds_bpermute — no LDS, no barrier.
// ---------------------------------------------------------------------------
__global__ __launch_bounds__(256) void energy_kernel(
    const float* __restrict__ x, const float* __restrict__ charges,
    const float* __restrict__ wfull, float* __restrict__ out,
    int n_rows, int n_waves) {
  const int lane = threadIdx.x & 63;
  const int wave = (int)((blockIdx.x * blockDim.x + threadIdx.x) >> 6);

  // ---- per-lane static setup (amortized over the grid-stride row loop) ----
  float4 w4[9];
  int cpack[9];  // 4 packed byte-addresses (cidx*4) per int
#pragma unroll
  for (int j = 0; j < 9; ++j) {
    const int f = lane + 64 * j;
    w4[j] = ((const float4*)wfull)[f];
    int p = 0;
#pragma unroll
    for (int m = 0; m < 4; ++m) {
      const int e = 4 * f + m;
      int c;
      if (e < 256)       c = 0;
      else if (e < 1024) c = 1 + (e - 256) % 3;
      else               c = 4 + (e - 1024) % 5;
      p |= (c * 4) << (8 * m);
    }
    cpack[j] = p;
  }

  for (int z = wave; z < n_rows; z += n_waves) {
    // lanes 0..8 hold the row's 9 charge components
    float chv = 0.f;
    if (lane < 9) chv = charges[z * 9 + lane];
    const int chvi = __float_as_int(chv);

    const float4* __restrict__ xr = (const float4*)(x + (size_t)z * ROWF);
    float acc = 0.f;
#pragma unroll
    for (int j = 0; j < 9; ++j) {
      const float4 v = xr[lane + 64 * j];
      const int p = cpack[j];
      const float c0 = __int_as_float(__builtin_amdgcn_ds_bpermute(p & 0xff, chvi));
      const float c1 = __int_as_float(__builtin_amdgcn_ds_bpermute((p >> 8) & 0xff, chvi));
      const float c2 = __int_as_float(__builtin_amdgcn_ds_bpermute((p >> 16) & 0xff, chvi));
      const float c3 = __int_as_float(__builtin_amdgcn_ds_bpermute((p >> 24) & 0xff, chvi));
      acc = fmaf(v.x, w4[j].x * c0, acc);
      acc = fmaf(v.y, w4[j].y * c1, acc);
      acc = fmaf(v.z, w4[j].z * c2, acc);
      acc = fmaf(v.w, w4[j].w * c3, acc);
    }
    // wave-level sum
#pragma unroll
    for (int off = 32; off > 0; off >>= 1) acc += __shfl_down(acc, off, 64);
    if (lane == 0) out[z] = acc;
  }
}

extern "C" void kernel_launch(void* const* d_in, const int* in_sizes, int n_in,
                              void* d_out, int out_size, void* d_ws, size_t ws_size,
                              hipStream_t stream) {
  const float* node_feats = (const float*)d_in[0];
  const float* charges    = (const float*)d_in[1];
  const float* W_lin0     = (const float*)d_in[2];
  const float* W_lin1     = (const float*)d_in[3];
  const float* W_lin2     = (const float*)d_in[4];
  const float* W_tp0      = (const float*)d_in[5];
  const float* W_tp1      = (const float*)d_in[6];
  const float* W_tp2      = (const float*)d_in[7];
  float* out   = (float*)d_out;
  float* wfull = (float*)d_ws;  // 2304 floats = 9216 B of scratch

  const int n_rows = in_sizes[0] / ROWF;

  build_wfull_kernel<<<3 * 256, 64, 0, stream>>>(W_lin0, W_lin1, W_lin2,
                                                 W_tp0, W_tp1, W_tp2, wfull);

  const int blocks  = 2048;           // 8192 waves -> 8 rows/wave at N=65536
  const int n_waves = blocks * (256 / 64);
  energy_kernel<<<blocks, 256, 0, stream>>>(node_feats, charges, wfull, out,
                                            n_rows, n_waves);
}

// Round 3
// 732.963 us; speedup vs baseline: 1.0558x; 1.0558x over previous
//
#include <hip/hip_runtime.h>
#include <math.h>

#define MULC 256
#define ROWF 2304   // 9*MUL floats per node row

typedef float f32x4 __attribute__((ext_vector_type(4)));

// ---------------------------------------------------------------------------
// Kernel 1: fold W_lin @ W_tp into a single expanded weight vector W_full[2304]
//   W_full[u]            = (W_lin0[u,:]·W_tp0) * alpha*lin_norm
//   W_full[256+u*3+i]    = (W_lin1[u,:]·W_tp1) * alpha*lin_norm/sqrt(3)
//   W_full[1024+u*5+i]   = (W_lin2[u,:]·W_tp2) * alpha*lin_norm/sqrt(5)
// ---------------------------------------------------------------------------
__global__ __launch_bounds__(64) void build_wfull_kernel(
    const float* __restrict__ Wl0, const float* __restrict__ Wl1,
    const float* __restrict__ Wl2, const float* __restrict__ Wt0,
    const float* __restrict__ Wt1, const float* __restrict__ Wt2,
    float* __restrict__ wfull) {
  const int b    = blockIdx.x;
  const int mat  = b >> 8;
  const int u    = b & 255;
  const int lane = threadIdx.x;  // 0..63

  const float* __restrict__ Wl = (mat == 0) ? Wl0 : (mat == 1) ? Wl1 : Wl2;
  const float* __restrict__ Wt = (mat == 0) ? Wt0 : (mat == 1) ? Wt1 : Wt2;

  float s = 0.f;
#pragma unroll
  for (int t = 0; t < 4; ++t) {
    const int v = lane + 64 * t;
    s = fmaf(Wl[u * MULC + v], Wt[v], s);
  }
#pragma unroll
  for (int off = 32; off > 0; off >>= 1) s += __shfl_down(s, off, 64);

  if (lane == 0) {
    const float base = 0.0625f / sqrtf(768.0f);  // lin_norm * alpha
    if (mat == 0) {
      wfull[u] = s * base;
    } else if (mat == 1) {
      const float sv = s * base * (1.0f / sqrtf(3.0f));
#pragma unroll
      for (int i = 0; i < 3; ++i) wfull[256 + u * 3 + i] = sv;
    } else {
      const float sv = s * base * (1.0f / sqrtf(5.0f));
#pragma unroll
      for (int i = 0; i < 5; ++i) wfull[1024 + u * 5 + i] = sv;
    }
  }
}

// ---------------------------------------------------------------------------
// Kernel 2: streaming weighted reduction.
//   energy[z] = sum_e x[z,e] * W_full[e] * ch[z, cidx(e)]
// One wave per row (grid-stride). Lane l handles float4 chunks f = l + 64*j.
// DS budget per row: 29 bpermutes (j=0 via readfirstlane SGPR broadcast;
// x1 j's reuse m=3's charge == m=0's) + 6 reduce shuffles.
// x is read once -> nontemporal loads keep L2 clean.
// ---------------------------------------------------------------------------
__global__ __launch_bounds__(256) void energy_kernel(
    const float* __restrict__ x, const float* __restrict__ charges,
    const float* __restrict__ wfull, float* __restrict__ out,
    int n_rows, int n_waves) {
  const int lane = threadIdx.x & 63;
  const int wave = (int)((blockIdx.x * blockDim.x + threadIdx.x) >> 6);

  // ---- per-lane static setup (amortized over the grid-stride row loop) ----
  f32x4 w4[9];
  int cpack[9];  // 4 packed byte-addresses (cidx*4) per int
#pragma unroll
  for (int j = 0; j < 9; ++j) {
    const int f = lane + 64 * j;
    w4[j] = ((const f32x4*)wfull)[f];
    int p = 0;
#pragma unroll
    for (int m = 0; m < 4; ++m) {
      const int e = 4 * f + m;
      int c;
      if (e < 256)       c = 0;
      else if (e < 1024) c = 1 + (e - 256) % 3;
      else               c = 4 + (e - 1024) % 5;
      p |= (c * 4) << (8 * m);
    }
    cpack[j] = p;
  }

  if (wave >= n_rows) return;

  // prime the charge pipeline for the first row
  float chv = 0.f;
  if (lane < 9) chv = charges[(size_t)wave * 9 + lane];

  for (int z = wave; z < n_rows; z += n_waves) {
    const int chvi = __float_as_int(chv);
    const float c0 = __int_as_float(__builtin_amdgcn_readfirstlane(chvi));

    // prefetch next row's charges (independent of this row's compute)
    const int zn = z + n_waves;
    float chv_next = 0.f;
    if (zn < n_rows && lane < 9) chv_next = charges[(size_t)zn * 9 + lane];

    const f32x4* __restrict__ xr = (const f32x4*)(x + (size_t)z * ROWF);
    float acc = 0.f;

    // ---- j = 0: all elements use charge component 0 (SGPR broadcast) ----
    {
      const f32x4 v = __builtin_nontemporal_load(&xr[lane]);
      acc = fmaf(v.x, w4[0].x * c0, acc);
      acc = fmaf(v.y, w4[0].y * c0, acc);
      acc = fmaf(v.z, w4[0].z * c0, acc);
      acc = fmaf(v.w, w4[0].w * c0, acc);
    }
    // ---- j = 1..3 (x1 region): charge of m=3 equals charge of m=0 ----
#pragma unroll
    for (int j = 1; j < 4; ++j) {
      const f32x4 v = __builtin_nontemporal_load(&xr[lane + 64 * j]);
      const int p = cpack[j];
      const float ca = __int_as_float(__builtin_amdgcn_ds_bpermute(p & 0xff, chvi));
      const float cb = __int_as_float(__builtin_amdgcn_ds_bpermute((p >> 8) & 0xff, chvi));
      const float cc = __int_as_float(__builtin_amdgcn_ds_bpermute((p >> 16) & 0xff, chvi));
      acc = fmaf(v.x, w4[j].x * ca, acc);
      acc = fmaf(v.y, w4[j].y * cb, acc);
      acc = fmaf(v.z, w4[j].z * cc, acc);
      acc = fmaf(v.w, w4[j].w * ca, acc);  // m=3 shares m=0's charge (mod 3)
    }
    // ---- j = 4..8 (x2 region): 4 distinct charges per float4 (mod 5) ----
#pragma unroll
    for (int j = 4; j < 9; ++j) {
      const f32x4 v = __builtin_nontemporal_load(&xr[lane + 64 * j]);
      const int p = cpack[j];
      const float ca = __int_as_float(__builtin_amdgcn_ds_bpermute(p & 0xff, chvi));
      const float cb = __int_as_float(__builtin_amdgcn_ds_bpermute((p >> 8) & 0xff, chvi));
      const float cc = __int_as_float(__builtin_amdgcn_ds_bpermute((p >> 16) & 0xff, chvi));
      const float cd = __int_as_float(__builtin_amdgcn_ds_bpermute((p >> 24) & 0xff, chvi));
      acc = fmaf(v.x, w4[j].x * ca, acc);
      acc = fmaf(v.y, w4[j].y * cb, acc);
      acc = fmaf(v.z, w4[j].z * cc, acc);
      acc = fmaf(v.w, w4[j].w * cd, acc);
    }

    // wave-level sum
#pragma unroll
    for (int off = 32; off > 0; off >>= 1) acc += __shfl_down(acc, off, 64);
    if (lane == 0) out[z] = acc;

    chv = chv_next;
  }
}

extern "C" void kernel_launch(void* const* d_in, const int* in_sizes, int n_in,
                              void* d_out, int out_size, void* d_ws, size_t ws_size,
                              hipStream_t stream) {
  const float* node_feats = (const float*)d_in[0];
  const float* charges    = (const float*)d_in[1];
  const float* W_lin0     = (const float*)d_in[2];
  const float* W_lin1     = (const float*)d_in[3];
  const float* W_lin2     = (const float*)d_in[4];
  const float* W_tp0      = (const float*)d_in[5];
  const float* W_tp1      = (const float*)d_in[6];
  const float* W_tp2      = (const float*)d_in[7];
  float* out   = (float*)d_out;
  float* wfull = (float*)d_ws;  // 2304 floats = 9216 B of scratch

  const int n_rows = in_sizes[0] / ROWF;

  build_wfull_kernel<<<3 * 256, 64, 0, stream>>>(W_lin0, W_lin1, W_lin2,
                                                 W_tp0, W_tp1, W_tp2, wfull);

  const int blocks  = 4096;            // 16384 waves -> 4 rows/wave at N=65536
  const int n_waves = blocks * (256 / 64);
  energy_kernel<<<blocks, 256, 0, stream>>>(node_feats, charges, wfull, out,
                                            n_rows, n_waves);
}